// Round 1
// baseline (234.691 us; speedup 1.0000x reference)
//
#include <hip/hip_runtime.h>

#define KC 512     // num codes
#define DC 64      // embedding dim
#define HW 4096    // H*W
#define NPTS 131072  // B*H*W = 32*4096
#define NBLK 512   // NPTS / 256

// --- kernel 1: codebook squared norms -------------------------------------
__global__ __launch_bounds__(512) void vq_norms(const float* __restrict__ cb,
                                                float* __restrict__ cbn) {
    int k = threadIdx.x;  // 512 threads, one per code
    float s = 0.f;
#pragma unroll
    for (int c = 0; c < DC; ++c) {
        float v = cb[k * DC + c];
        s = fmaf(v, v, s);
    }
    cbn[k] = s;
}

// --- kernel 2: nearest-code search + gather + loss partials ----------------
__global__ __launch_bounds__(256) void vq_main(const float* __restrict__ z,
                                               const float* __restrict__ cb,
                                               const float* __restrict__ cbn,
                                               float* __restrict__ outq,
                                               float* __restrict__ partial) {
    const int tid = threadIdx.x;
    const int n = blockIdx.x * 256 + tid;      // point index, < NPTS exactly
    const int b = n >> 12;                     // n / HW
    const int s = n & (HW - 1);                // n % HW
    const float* zp = z + (size_t)b * (DC * HW) + s;

    // load this point's 64 channels (coalesced across lanes: stride-1 in s)
    float zr[DC];
#pragma unroll
    for (int c = 0; c < DC; ++c) zr[c] = zp[(size_t)c * HW];

    // argmin_k ||e_k||^2 - 2 z.e_k   (||z||^2 constant per point, dropped)
    float best = 3.4e38f;
    int bidx = 0;
    for (int k = 0; k < KC; ++k) {
        const float* e = cb + k * DC;          // wave-uniform -> s_load
        float a0 = 0.f, a1 = 0.f, a2 = 0.f, a3 = 0.f;
#pragma unroll
        for (int c = 0; c < DC; c += 4) {
            a0 = fmaf(zr[c + 0], e[c + 0], a0);
            a1 = fmaf(zr[c + 1], e[c + 1], a1);
            a2 = fmaf(zr[c + 2], e[c + 2], a2);
            a3 = fmaf(zr[c + 3], e[c + 3], a3);
        }
        float dist = cbn[k] - 2.f * ((a0 + a1) + (a2 + a3));
        if (dist < best) { best = dist; bidx = k; }  // strict < keeps first min
    }

    // gather winning code, write output (same layout as z), loss partial
    const float* eb = cb + (size_t)bidx * DC;
    float* op = outq + (size_t)b * (DC * HW) + s;
    float err = 0.f;
#pragma unroll
    for (int c = 0; c < DC; ++c) {
        float q = eb[c];
        op[(size_t)c * HW] = q;
        float d = q - zr[c];
        err = fmaf(d, d, err);
    }

    // block-reduce err (256 threads = 4 waves)
#pragma unroll
    for (int off = 32; off > 0; off >>= 1) err += __shfl_down(err, off);
    __shared__ float red[4];
    if ((tid & 63) == 0) red[tid >> 6] = err;
    __syncthreads();
    if (tid == 0) partial[blockIdx.x] = (red[0] + red[1]) + (red[2] + red[3]);
}

// --- kernel 3: final loss reduction ----------------------------------------
__global__ __launch_bounds__(256) void vq_loss(const float* __restrict__ partial,
                                               float* __restrict__ loss_out) {
    int tid = threadIdx.x;
    float s = partial[tid] + partial[tid + 256];   // 512 partials
#pragma unroll
    for (int off = 32; off > 0; off >>= 1) s += __shfl_down(s, off);
    __shared__ float red[4];
    if ((tid & 63) == 0) red[tid >> 6] = s;
    __syncthreads();
    if (tid == 0) {
        float total = (red[0] + red[1]) + (red[2] + red[3]);
        // loss = q_latent + 0.25*e_latent = 1.25 * mean((q-z)^2)
        loss_out[0] = 1.25f * total / 8388608.0f;
    }
}

extern "C" void kernel_launch(void* const* d_in, const int* in_sizes, int n_in,
                              void* d_out, int out_size, void* d_ws, size_t ws_size,
                              hipStream_t stream) {
    const float* z  = (const float*)d_in[0];   // [32,64,64,64] f32
    const float* cb = (const float*)d_in[1];   // [512,64] f32
    float* outq = (float*)d_out;               // 8388608 floats + 1 loss
    float* loss = outq + 8388608;

    float* cbn     = (float*)d_ws;             // 512 floats
    float* partial = cbn + KC;                 // 512 floats

    vq_norms<<<1, 512, 0, stream>>>(cb, cbn);
    vq_main<<<NBLK, 256, 0, stream>>>(z, cb, cbn, outq, partial);
    vq_loss<<<1, 256, 0, stream>>>(partial, loss);
}

// Round 2
// 95.381 us; speedup vs baseline: 2.4606x; 2.4606x over previous
//
#include <hip/hip_runtime.h>
#include <hip/hip_bf16.h>

typedef short bf16x8 __attribute__((ext_vector_type(8)));
typedef short s16x4  __attribute__((ext_vector_type(4)));
typedef float f32x4  __attribute__((ext_vector_type(4)));

#define KC 512
#define DC 64
#define HWs 4096          // H*W
#define NPTS 131072       // 32*64*64
#define NWAVES 8192       // NPTS/16

static __device__ inline short f2b(float f) {
    __hip_bfloat16 h = __float2bfloat16(f);      // RNE
    return *reinterpret_cast<short*>(&h);
}

// --- prep 1: codebook fp32 -> bf16 (coalesced, 8192 threads x 4 elems) -----
__global__ __launch_bounds__(256) void vq_cvt(const float* __restrict__ cbf,
                                              short* __restrict__ cbb) {
    int i = blockIdx.x * 256 + threadIdx.x;      // 0..8191
    f32x4 v = *reinterpret_cast<const f32x4*>(cbf + (size_t)i * 4);
    s16x4 o;
    o[0] = f2b(v[0]); o[1] = f2b(v[1]); o[2] = f2b(v[2]); o[3] = f2b(v[3]);
    *reinterpret_cast<s16x4*>(cbb + (size_t)i * 4) = o;
}

// --- prep 2: codebook squared norms (fp32) ---------------------------------
__global__ __launch_bounds__(256) void vq_norms(const float* __restrict__ cbf,
                                                float* __restrict__ cbn) {
    int k = blockIdx.x * 256 + threadIdx.x;      // 0..511
    const f32x4* row = reinterpret_cast<const f32x4*>(cbf + (size_t)k * DC);
    float s = 0.f;
#pragma unroll
    for (int q = 0; q < DC / 4; ++q) {
        f32x4 v = row[q];
        s = fmaf(v[0], v[0], s); s = fmaf(v[1], v[1], s);
        s = fmaf(v[2], v[2], s); s = fmaf(v[3], v[3], s);
    }
    cbn[k] = s;
}

// --- main: MFMA nearest-code search + gather + loss partials ---------------
// One wave per 16 points. A = codebook tile (16 codes x 32 dims, bf16),
// B = z tile (32 dims x 16 points, bf16), D[code][point] fp32.
__global__ __launch_bounds__(256) void vq_search(const float* __restrict__ z,
                                                 const float* __restrict__ cbf,
                                                 const short* __restrict__ cbb,
                                                 const float* __restrict__ cbn,
                                                 float* __restrict__ outq,
                                                 float* __restrict__ partial) {
    const int lane = threadIdx.x & 63;
    const int wid  = threadIdx.x >> 6;
    const int wgid = blockIdx.x * 4 + wid;       // 0..8191
    const int p0 = wgid * 16;
    const int b  = p0 >> 12;                     // 16 | 4096, so same b for all 16
    const int g  = lane >> 4;                    // k-group / reg-group
    const int pl = lane & 15;                    // point (B col, D col) and A row
    const int s  = (p0 & (HWs - 1)) + pl;

    const float* zbase = z + (size_t)b * (DC * HWs) + s;

    // load 16 z values for this lane: dims 8g+j (k-grp 0) and 32+8g+j (k-grp 1)
    float zf[16];
#pragma unroll
    for (int j = 0; j < 8; ++j) {
        zf[j]     = zbase[(size_t)(8 * g + j) * HWs];
        zf[j + 8] = zbase[(size_t)(32 + 8 * g + j) * HWs];
    }
    bf16x8 zb0, zb1;
#pragma unroll
    for (int j = 0; j < 8; ++j) { zb0[j] = f2b(zf[j]); zb1[j] = f2b(zf[j + 8]); }

    float best = 3.4e38f;
    int bidx = 0;
    for (int t = 0; t < KC / 16; ++t) {          // 32 code tiles
        const short* ap = cbb + (size_t)(16 * t + pl) * DC + 8 * g;
        bf16x8 a0 = *reinterpret_cast<const bf16x8*>(ap);
        bf16x8 a1 = *reinterpret_cast<const bf16x8*>(ap + 32);
        f32x4 acc = {0.f, 0.f, 0.f, 0.f};
        acc = __builtin_amdgcn_mfma_f32_16x16x32_bf16(a0, zb0, acc, 0, 0, 0);
        acc = __builtin_amdgcn_mfma_f32_16x16x32_bf16(a1, zb1, acc, 0, 0, 0);
        f32x4 cn = *reinterpret_cast<const f32x4*>(cbn + 16 * t + 4 * g);
#pragma unroll
        for (int j = 0; j < 4; ++j) {
            float sc = fmaf(-2.f, acc[j], cn[j]);    // ||e||^2 - 2 z.e
            int code = 16 * t + 4 * g + j;           // row = 4g+j in this tile
            bool lt = sc < best;                     // strict <: first min in-lane
            best = lt ? sc : best;
            bidx = lt ? code : bidx;
        }
    }

    // argmin across the 4 lane-groups holding the same point (xor 16, 32)
#pragma unroll
    for (int m = 16; m <= 32; m <<= 1) {
        float ob = __shfl_xor(best, m, 64);
        int   oi = __shfl_xor(bidx, m, 64);
        if (ob < best || (ob == best && oi < bidx)) { best = ob; bidx = oi; }
    }

    // epilogue: gather winning code (fp32), write out, loss partial
    const float* qrow = cbf + (size_t)bidx * DC + 8 * g;
    float* obase = outq + (size_t)b * (DC * HWs) + s;
    float err = 0.f;
#pragma unroll
    for (int j = 0; j < 8; ++j) {
        float q0 = qrow[j];
        float q1 = qrow[32 + j];
        obase[(size_t)(8 * g + j) * HWs]      = q0;
        obase[(size_t)(32 + 8 * g + j) * HWs] = q1;
        float d0 = q0 - zf[j], d1 = q1 - zf[j + 8];
        err = fmaf(d0, d0, err);
        err = fmaf(d1, d1, err);
    }

    // full-wave reduce (16 points x their 4 lane-groups = all 64 lanes)
#pragma unroll
    for (int off = 32; off; off >>= 1) err += __shfl_down(err, off, 64);
    if (lane == 0) partial[wgid] = err;
}

// --- final loss reduction ---------------------------------------------------
__global__ __launch_bounds__(256) void vq_loss(const float* __restrict__ partial,
                                               float* __restrict__ loss_out) {
    float s = 0.f;
    for (int i = threadIdx.x; i < NWAVES; i += 256) s += partial[i];
#pragma unroll
    for (int off = 32; off; off >>= 1) s += __shfl_down(s, off, 64);
    __shared__ float red[4];
    if ((threadIdx.x & 63) == 0) red[threadIdx.x >> 6] = s;
    __syncthreads();
    if (threadIdx.x == 0)
        loss_out[0] = 1.25f * ((red[0] + red[1]) + (red[2] + red[3])) / 8388608.0f;
}

extern "C" void kernel_launch(void* const* d_in, const int* in_sizes, int n_in,
                              void* d_out, int out_size, void* d_ws, size_t ws_size,
                              hipStream_t stream) {
    const float* z   = (const float*)d_in[0];    // [32,64,64,64] f32
    const float* cbf = (const float*)d_in[1];    // [512,64] f32
    float* outq = (float*)d_out;                 // 8388608 + 1 (loss)
    float* loss = outq + 8388608;

    short* cbb     = (short*)d_ws;                       // 512*64 bf16 = 64 KB
    float* cbn     = (float*)((char*)d_ws + 65536);      // 512 f32
    float* partial = (float*)((char*)d_ws + 65536 + 2048); // 8192 f32

    vq_cvt<<<32, 256, 0, stream>>>(cbf, cbb);
    vq_norms<<<2, 256, 0, stream>>>(cbf, cbn);
    vq_search<<<NPTS / 64, 256, 0, stream>>>(z, cbf, cbb, cbn, outq, partial);
    vq_loss<<<1, 256, 0, stream>>>(partial, loss);
}

// Round 3
// 67.500 us; speedup vs baseline: 3.4769x; 1.4130x over previous
//
#include <hip/hip_runtime.h>
#include <hip/hip_bf16.h>

typedef short bf16x8 __attribute__((ext_vector_type(8)));
typedef short s16x4  __attribute__((ext_vector_type(4)));
typedef float f32x4  __attribute__((ext_vector_type(4)));

#define KC 512
#define DC 64
#define HWs 4096
#define NPTS 131072
#define PPW 32                      // points per wave
#define NWAVES (NPTS / PPW)         // 4096

static __device__ inline short f2b(float f) {
    __hip_bfloat16 h = __float2bfloat16(f);      // RNE
    return *reinterpret_cast<short*>(&h);
}

// --- prep: codebook fp32->bf16 + squared norms (fused, coalesced) ----------
__global__ __launch_bounds__(256) void vq_prep(const float* __restrict__ cbf,
                                               short* __restrict__ cbb,
                                               float* __restrict__ cbn) {
    int i = blockIdx.x * 256 + threadIdx.x;      // 0..8191, 4 floats each
    f32x4 v = *reinterpret_cast<const f32x4*>(cbf + (size_t)i * 4);
    s16x4 o;
    o[0] = f2b(v[0]); o[1] = f2b(v[1]); o[2] = f2b(v[2]); o[3] = f2b(v[3]);
    *reinterpret_cast<s16x4*>(cbb + (size_t)i * 4) = o;
    float ss = fmaf(v[0], v[0], fmaf(v[1], v[1], fmaf(v[2], v[2], v[3] * v[3])));
    // 16 consecutive threads hold one codebook row
    ss += __shfl_down(ss, 8, 16);
    ss += __shfl_down(ss, 4, 16);
    ss += __shfl_down(ss, 2, 16);
    ss += __shfl_down(ss, 1, 16);
    if ((threadIdx.x & 15) == 0) cbn[i >> 4] = ss;
}

// --- main: MFMA nearest-code search, 32 points per wave --------------------
// A = 16 codes x 32 dims (bf16), B = 32 dims x 16 points; two B-frags/wave.
__global__ __launch_bounds__(256) void vq_search(const float* __restrict__ z,
                                                 const float* __restrict__ cbf,
                                                 const short* __restrict__ cbb,
                                                 const float* __restrict__ cbn,
                                                 float* __restrict__ outq,
                                                 float* __restrict__ partial) {
    const int lane = threadIdx.x & 63;
    const int wid  = threadIdx.x >> 6;
    const int wgid = blockIdx.x * 4 + wid;       // 0..4095
    const int p0 = wgid * PPW;
    const int b  = p0 >> 12;                     // 32 | 4096 -> same b for all
    const int g  = lane >> 4;                    // k-group / acc row group
    const int pl = lane & 15;                    // point-in-frag, A row
    const int s0 = (p0 & (HWs - 1)) + pl;
    const int d0 = 8 * g;

    const float* zbase = z + (size_t)b * (DC * HWs) + s0;

    // B-frags: zb[f][h] = dims 32h+d0+j of point s0+16f (bf16)
    bf16x8 zb[2][2];
#pragma unroll
    for (int f = 0; f < 2; ++f)
#pragma unroll
        for (int h = 0; h < 2; ++h)
#pragma unroll
            for (int j = 0; j < 8; ++j)
                zb[f][h][j] = f2b(zbase[(size_t)(32 * h + d0 + j) * HWs + 16 * f]);

    float best0 = 3.4e38f, best1 = 3.4e38f;
    int bidx0 = 0, bidx1 = 0;
#pragma unroll 4
    for (int t = 0; t < KC / 16; ++t) {
        const short* ap = cbb + (size_t)(16 * t + pl) * DC + d0;
        bf16x8 a0 = *reinterpret_cast<const bf16x8*>(ap);
        bf16x8 a1 = *reinterpret_cast<const bf16x8*>(ap + 32);
        f32x4 acc0 = {0.f, 0.f, 0.f, 0.f};
        f32x4 acc1 = {0.f, 0.f, 0.f, 0.f};
        acc0 = __builtin_amdgcn_mfma_f32_16x16x32_bf16(a0, zb[0][0], acc0, 0, 0, 0);
        acc0 = __builtin_amdgcn_mfma_f32_16x16x32_bf16(a1, zb[0][1], acc0, 0, 0, 0);
        acc1 = __builtin_amdgcn_mfma_f32_16x16x32_bf16(a0, zb[1][0], acc1, 0, 0, 0);
        acc1 = __builtin_amdgcn_mfma_f32_16x16x32_bf16(a1, zb[1][1], acc1, 0, 0, 0);
        f32x4 cn = *reinterpret_cast<const f32x4*>(cbn + 16 * t + 4 * g);
#pragma unroll
        for (int j = 0; j < 4; ++j) {
            int code = 16 * t + 4 * g + j;
            float sc0 = fmaf(-2.f, acc0[j], cn[j]);   // ||e||^2 - 2 z.e
            if (sc0 < best0) { best0 = sc0; bidx0 = code; }
            float sc1 = fmaf(-2.f, acc1[j], cn[j]);
            if (sc1 < best1) { best1 = sc1; bidx1 = code; }
        }
    }

    // argmin across the 4 g-groups holding the same point
#pragma unroll
    for (int m = 16; m <= 32; m <<= 1) {
        float ob = __shfl_xor(best0, m, 64); int oi = __shfl_xor(bidx0, m, 64);
        if (ob < best0 || (ob == best0 && oi < bidx0)) { best0 = ob; bidx0 = oi; }
        ob = __shfl_xor(best1, m, 64); oi = __shfl_xor(bidx1, m, 64);
        if (ob < best1 || (ob == best1 && oi < bidx1)) { best1 = ob; bidx1 = oi; }
    }

    // epilogue: gather fp32 code, write out, loss partial (z reloaded, cached)
    float err = 0.f;
    float* obase = outq + (size_t)b * (DC * HWs) + s0;
#pragma unroll
    for (int f = 0; f < 2; ++f) {
        const int bi = f ? bidx1 : bidx0;
        const float* qrow = cbf + (size_t)bi * DC + d0;
#pragma unroll
        for (int h = 0; h < 2; ++h)
#pragma unroll
            for (int j = 0; j < 8; ++j) {
                float q = qrow[32 * h + j];
                size_t off = (size_t)(32 * h + d0 + j) * HWs + 16 * f;
                float zv = zbase[off];
                obase[off] = q;
                float d = q - zv;
                err = fmaf(d, d, err);
            }
    }

#pragma unroll
    for (int off = 32; off; off >>= 1) err += __shfl_down(err, off, 64);
    if (lane == 0) partial[wgid] = err;
}

// --- final loss reduction ---------------------------------------------------
__global__ __launch_bounds__(256) void vq_loss(const float* __restrict__ partial,
                                               float* __restrict__ loss_out) {
    float s = 0.f;
    for (int i = threadIdx.x; i < NWAVES; i += 256) s += partial[i];
#pragma unroll
    for (int off = 32; off; off >>= 1) s += __shfl_down(s, off, 64);
    __shared__ float red[4];
    if ((threadIdx.x & 63) == 0) red[threadIdx.x >> 6] = s;
    __syncthreads();
    if (threadIdx.x == 0)
        loss_out[0] = 1.25f * ((red[0] + red[1]) + (red[2] + red[3])) / 8388608.0f;
}

extern "C" void kernel_launch(void* const* d_in, const int* in_sizes, int n_in,
                              void* d_out, int out_size, void* d_ws, size_t ws_size,
                              hipStream_t stream) {
    const float* z   = (const float*)d_in[0];    // [32,64,64,64] f32
    const float* cbf = (const float*)d_in[1];    // [512,64] f32
    float* outq = (float*)d_out;                 // 8388608 + 1 (loss)
    float* loss = outq + 8388608;

    short* cbb     = (short*)d_ws;                         // 64 KB bf16 codebook
    float* cbn     = (float*)((char*)d_ws + 65536);        // 512 f32 norms
    float* partial = (float*)((char*)d_ws + 65536 + 2048); // 4096 f32 partials

    vq_prep<<<32, 256, 0, stream>>>(cbf, cbb, cbn);
    vq_search<<<NWAVES / 4, 256, 0, stream>>>(z, cbf, cbb, cbn, outq, partial);
    vq_loss<<<1, 256, 0, stream>>>(partial, loss);
}

// Round 4
// 40.426 us; speedup vs baseline: 5.8055x; 1.6697x over previous
//
#include <hip/hip_runtime.h>
#include <hip/hip_bf16.h>

typedef short bf16x8 __attribute__((ext_vector_type(8)));
typedef float f32x4  __attribute__((ext_vector_type(4)));

#define KC 512
#define DC 64
#define HWs 4096
#define NPTS 131072
#define PPW 32                       // points per wave
#define NWAVES (NPTS / PPW)          // 4096
#define WPB 16                       // waves per block (1024 threads)
#define NBLK (NWAVES / WPB)          // 256 blocks = 1 per CU

static __device__ inline short f2b(float f) {
    __hip_bfloat16 h = __float2bfloat16(f);   // RNE
    return *reinterpret_cast<short*>(&h);
}

// --- prep: cnb[k] = 1 - 0.5*||e_k||^2  (accumulator init; argmax form) -----
__global__ __launch_bounds__(256) void vq_prep(const float* __restrict__ cbf,
                                               float* __restrict__ cnb) {
    int i = blockIdx.x * 256 + threadIdx.x;   // 0..8191, one f32x4 each
    f32x4 v = *reinterpret_cast<const f32x4*>(cbf + (size_t)i * 4);
    float ss = fmaf(v[0], v[0], fmaf(v[1], v[1], fmaf(v[2], v[2], v[3] * v[3])));
    ss += __shfl_down(ss, 8, 16);
    ss += __shfl_down(ss, 4, 16);
    ss += __shfl_down(ss, 2, 16);
    ss += __shfl_down(ss, 1, 16);
    if ((threadIdx.x & 15) == 0) cnb[i >> 4] = 1.0f - 0.5f * ss;
}

// --- main: LDS-staged codebook, MFMA search, packed argmax -----------------
__global__ __launch_bounds__(1024, 4) void vq_search(const float* __restrict__ z,
                                                     const float* __restrict__ cbf,
                                                     const float* __restrict__ cnb,
                                                     float* __restrict__ outq,
                                                     float* __restrict__ partial) {
    __shared__ short lds_cb[KC * DC];          // 64 KB, 16B slots XOR-swizzled
    char* ldsc = (char*)lds_cb;
    const int tid = threadIdx.x;

    // stage: fp32 codebook -> bf16 LDS, slot' = slot ^ (row & 7)
    {
        const int r = tid >> 1, hf = tid & 1, r7 = r & 7;
        const float* src = cbf + (size_t)r * DC + hf * 32;
#pragma unroll
        for (int q = 0; q < 4; ++q) {
            f32x4 v0 = *reinterpret_cast<const f32x4*>(src + q * 8);
            f32x4 v1 = *reinterpret_cast<const f32x4*>(src + q * 8 + 4);
            bf16x8 o;
            o[0] = f2b(v0[0]); o[1] = f2b(v0[1]); o[2] = f2b(v0[2]); o[3] = f2b(v0[3]);
            o[4] = f2b(v1[0]); o[5] = f2b(v1[1]); o[6] = f2b(v1[2]); o[7] = f2b(v1[3]);
            int slot = (hf * 4 + q) ^ r7;
            *reinterpret_cast<bf16x8*>(ldsc + r * 128 + slot * 16) = o;
        }
    }
    __syncthreads();

    const int lane = tid & 63;
    const int wid  = tid >> 6;
    const int wgid = blockIdx.x * WPB + wid;   // 0..4095
    const int p0 = wgid * PPW;
    const int b  = p0 >> 12;                   // 32 | 4096 -> same b for wave
    const int g  = lane >> 4;
    const int pl = lane & 15;
    const int s0 = (p0 & (HWs - 1)) + pl;
    const int d0 = 8 * g;

    const float* zbase = z + (size_t)b * (DC * HWs) + s0;

    // z: keep fp32 in regs for loss, bf16 frags for MFMA
    float  zf[2][16];
    bf16x8 zb[2][2];
#pragma unroll
    for (int f = 0; f < 2; ++f)
#pragma unroll
        for (int h = 0; h < 2; ++h)
#pragma unroll
            for (int j = 0; j < 8; ++j) {
                float v = zbase[(size_t)(32 * h + d0 + j) * HWs + 16 * f];
                zf[f][8 * h + j] = v;
                zb[f][h][j] = f2b(v);
            }

    const int off0 = pl * 128 + ((g ^ (pl & 7)) * 16);        // dims 0..31
    const int off1 = pl * 128 + (((4 + g) ^ (pl & 7)) * 16);  // dims 32..63
    unsigned best0 = 0u, best1 = 0u;           // packed: bits(score)|code
#pragma unroll 4
    for (int t = 0; t < KC / 16; ++t) {
        bf16x8 a0 = *reinterpret_cast<const bf16x8*>(ldsc + t * 2048 + off0);
        bf16x8 a1 = *reinterpret_cast<const bf16x8*>(ldsc + t * 2048 + off1);
        f32x4 ini = *reinterpret_cast<const f32x4*>(cnb + t * 16 + 4 * g);
        f32x4 acc0 = ini, acc1 = ini;          // score = 1 - ||e||^2/2 + z.e
        acc0 = __builtin_amdgcn_mfma_f32_16x16x32_bf16(a0, zb[0][0], acc0, 0, 0, 0);
        acc0 = __builtin_amdgcn_mfma_f32_16x16x32_bf16(a1, zb[0][1], acc0, 0, 0, 0);
        acc1 = __builtin_amdgcn_mfma_f32_16x16x32_bf16(a0, zb[1][0], acc1, 0, 0, 0);
        acc1 = __builtin_amdgcn_mfma_f32_16x16x32_bf16(a1, zb[1][1], acc1, 0, 0, 0);
#pragma unroll
        for (int j = 0; j < 4; ++j) {
            unsigned code = (unsigned)(16 * t + 4 * g + j);   // 9 bits
            unsigned u0 = __float_as_uint(acc0[j]) | code;    // positive -> monotone
            unsigned u1 = __float_as_uint(acc1[j]) | code;
            best0 = best0 > u0 ? best0 : u0;
            best1 = best1 > u1 ? best1 : u1;
        }
    }

    // argmax across the 4 g-groups holding the same point
#pragma unroll
    for (int m = 16; m <= 32; m <<= 1) {
        unsigned o0 = (unsigned)__shfl_xor((int)best0, m, 64);
        unsigned o1 = (unsigned)__shfl_xor((int)best1, m, 64);
        best0 = best0 > o0 ? best0 : o0;
        best1 = best1 > o1 ? best1 : o1;
    }
    const int bidx0 = best0 & 511, bidx1 = best1 & 511;

    // epilogue: gather fp32 code, write out, loss partial (z from regs)
    float err = 0.f;
    float* obase = outq + (size_t)b * (DC * HWs) + s0;
#pragma unroll
    for (int f = 0; f < 2; ++f) {
        const float* qrow = cbf + (size_t)(f ? bidx1 : bidx0) * DC + d0;
#pragma unroll
        for (int h = 0; h < 2; ++h) {
            f32x4 q0 = *reinterpret_cast<const f32x4*>(qrow + 32 * h);
            f32x4 q1 = *reinterpret_cast<const f32x4*>(qrow + 32 * h + 4);
#pragma unroll
            for (int j = 0; j < 4; ++j) {
                size_t o = (size_t)(32 * h + d0 + j) * HWs + 16 * f;
                obase[o] = q0[j];
                float d = q0[j] - zf[f][8 * h + j];
                err = fmaf(d, d, err);
            }
#pragma unroll
            for (int j = 0; j < 4; ++j) {
                size_t o = (size_t)(32 * h + d0 + 4 + j) * HWs + 16 * f;
                obase[o] = q1[j];
                float d = q1[j] - zf[f][8 * h + 4 + j];
                err = fmaf(d, d, err);
            }
        }
    }

#pragma unroll
    for (int off = 32; off; off >>= 1) err += __shfl_down(err, off, 64);
    if (lane == 0) partial[wgid] = err;
}

// --- final loss reduction ---------------------------------------------------
__global__ __launch_bounds__(256) void vq_loss(const float* __restrict__ partial,
                                               float* __restrict__ loss_out) {
    float s = 0.f;
    for (int i = threadIdx.x; i < NWAVES; i += 256) s += partial[i];
#pragma unroll
    for (int off = 32; off; off >>= 1) s += __shfl_down(s, off, 64);
    __shared__ float red[4];
    if ((threadIdx.x & 63) == 0) red[threadIdx.x >> 6] = s;
    __syncthreads();
    if (threadIdx.x == 0)
        loss_out[0] = 1.25f * ((red[0] + red[1]) + (red[2] + red[3])) / 8388608.0f;
}

extern "C" void kernel_launch(void* const* d_in, const int* in_sizes, int n_in,
                              void* d_out, int out_size, void* d_ws, size_t ws_size,
                              hipStream_t stream) {
    const float* z   = (const float*)d_in[0];    // [32,64,64,64] f32
    const float* cbf = (const float*)d_in[1];    // [512,64] f32
    float* outq = (float*)d_out;                 // 8388608 + 1 (loss)
    float* loss = outq + 8388608;

    float* cnb     = (float*)d_ws;               // 512 f32 acc-init values
    float* partial = cnb + KC;                   // 4096 f32 partials

    vq_prep<<<32, 256, 0, stream>>>(cbf, cnb);
    vq_search<<<NBLK, 1024, 0, stream>>>(z, cbf, cnb, outq, partial);
    vq_loss<<<1, 256, 0, stream>>>(partial, loss);
}

// Round 6
// 32.641 us; speedup vs baseline: 7.1901x; 1.2385x over previous
//
#include <hip/hip_runtime.h>

typedef float f32x4 __attribute__((ext_vector_type(4)));
typedef int   i32x4 __attribute__((ext_vector_type(4)));

#define KC 512
#define DC 64
#define HWs 4096
#define NPTS 131072
#define NWAVES 8192            // 16 points per wave
#define SCALE 512.0f
#define INV_SCALE 0.001953125f
#define CBASE 256.0f           // keeps packed scores positive

template <bool HI>
static __device__ inline int pk8(float a, float b, int old) {
    return __builtin_amdgcn_cvt_pk_fp8_f32(a, b, old, HI);
}
template <int S>
static __device__ inline float dec8(int w) {
    return __builtin_amdgcn_cvt_f32_fp8(w, S);
}
static __device__ inline long mk64(int lo, int hi) {
    return (long)(((unsigned long)(unsigned)hi << 32) | (unsigned)lo);
}
static __device__ inline int pack4(float a, float b, float c, float d) {
    int w = pk8<false>(a, b, 0);
    return pk8<true>(c, d, w);
}

// --- prep: codebook -> fp8 (x512, chunk-interleaved) + score init ----------
// thread (r,g) handles dims [8g..8g+7] and [32+8g..32+8g+7] of row r; the 16
// fp8 bytes land contiguously at cb8[r*64 + g*16] so one ds_read_b128 later
// yields both K-tile A-frags.
__global__ __launch_bounds__(256) void vq_prep(const float* __restrict__ cbf,
                                               unsigned int* __restrict__ cb8,
                                               float* __restrict__ inib) {
    int i = blockIdx.x * 256 + threadIdx.x;   // 0..2047
    int r = i >> 2, g = i & 3;
    const float* src = cbf + (size_t)r * DC + 8 * g;
    f32x4 a0 = *(const f32x4*)(src);
    f32x4 a1 = *(const f32x4*)(src + 4);
    f32x4 b0 = *(const f32x4*)(src + 32);
    f32x4 b1 = *(const f32x4*)(src + 36);
    a0 *= SCALE; a1 *= SCALE; b0 *= SCALE; b1 *= SCALE;
    i32x4 w = {pack4(a0[0], a0[1], a0[2], a0[3]),
               pack4(a1[0], a1[1], a1[2], a1[3]),
               pack4(b0[0], b0[1], b0[2], b0[3]),
               pack4(b1[0], b1[1], b1[2], b1[3])};
    *(i32x4*)(cb8 + (size_t)i * 4) = w;
    float ss = 0.f;
#pragma unroll
    for (int j = 0; j < 4; ++j) {
        ss = fmaf(a0[j], a0[j], ss); ss = fmaf(a1[j], a1[j], ss);
        ss = fmaf(b0[j], b0[j], ss); ss = fmaf(b1[j], b1[j], ss);
    }
    ss += __shfl_xor(ss, 1, 64);
    ss += __shfl_xor(ss, 2, 64);              // sum over the row's 4 chunks
    if (g == 0) inib[r] = CBASE - 0.5f * ss;  // argmax(init + z.E')
}

// --- main: LDS fp8 codebook, MFMA search, packed argmax --------------------
__global__ __launch_bounds__(512, 8) void vq_search(const float* __restrict__ z,
                                                    const unsigned int* __restrict__ cb8,
                                                    const float* __restrict__ inib,
                                                    float* __restrict__ outq,
                                                    float* __restrict__ partial) {
    __shared__ unsigned int cbL[KC * 16];     // 32 KB fp8 codebook image
    __shared__ float iniL[KC];                // 2 KB score inits
    const int tid = threadIdx.x;

    // stage 34 KB global -> LDS (coalesced int4 copies)
    {
        const i32x4* srcv = (const i32x4*)cb8;
        i32x4* dstv = (i32x4*)cbL;
#pragma unroll
        for (int q = 0; q < 4; ++q) dstv[tid + q * 512] = srcv[tid + q * 512];
        iniL[tid] = inib[tid];
    }
    __syncthreads();

    const int lane = tid & 63, wid = tid >> 6;
    const int wgid = blockIdx.x * 8 + wid;    // 0..8191
    const int p0 = wgid * 16;
    const int b  = p0 >> 12;                  // 16 | 4096 -> same b for wave
    const int g  = lane >> 4, pl = lane & 15;
    const int s0 = (p0 & (HWs - 1)) + pl;
    const float* zbase = z + (size_t)b * (DC * HWs) + s0;

    // z -> fp8 B-frags (dims 8g+j and 32+8g+j of point pl); z NOT kept in regs
    long zfr0, zfr1;
    {
        float zt[16];
#pragma unroll
        for (int j = 0; j < 8; ++j) {
            zt[j]     = zbase[(size_t)(8 * g + j) * HWs];
            zt[8 + j] = zbase[(size_t)(32 + 8 * g + j) * HWs];
        }
        zfr0 = mk64(pack4(zt[0],  zt[1],  zt[2],  zt[3]),
                    pack4(zt[4],  zt[5],  zt[6],  zt[7]));
        zfr1 = mk64(pack4(zt[8],  zt[9],  zt[10], zt[11]),
                    pack4(zt[12], zt[13], zt[14], zt[15]));
    }

    unsigned best = 0u;
#pragma unroll 2
    for (int t = 0; t < KC / 16; ++t) {
        i32x4 aw = *(const i32x4*)(cbL + (size_t)(16 * t + pl) * 16 + g * 4);
        long A0 = mk64(aw[0], aw[1]);          // dims 8g..8g+7   (K-tile 0)
        long A1 = mk64(aw[2], aw[3]);          // dims 32+8g..+7  (K-tile 1)
        f32x4 acc = *(const f32x4*)(iniL + 16 * t + 4 * g);
        acc = __builtin_amdgcn_mfma_f32_16x16x32_fp8_fp8(A0, zfr0, acc, 0, 0, 0);
        acc = __builtin_amdgcn_mfma_f32_16x16x32_fp8_fp8(A1, zfr1, acc, 0, 0, 0);
#pragma unroll
        for (int j = 0; j < 4; ++j) {
            unsigned u = __builtin_bit_cast(unsigned, acc[j]) | (unsigned)(16 * t + 4 * g + j);
            best = best > u ? best : u;
        }
    }

    // argmax across the 4 g-groups holding the same point
#pragma unroll
    for (int m = 16; m <= 32; m <<= 1) {
        unsigned o = (unsigned)__shfl_xor((int)best, m, 64);
        best = best > o ? best : o;
    }
    const int bidx = best & 511;

    // epilogue: gather winning code from LDS, decode (const selectors),
    // write out, loss partial
    i32x4 qw = *(const i32x4*)(cbL + (size_t)bidx * 16 + g * 4);
    float qv[16];
#pragma unroll
    for (int w = 0; w < 4; ++w) {
        qv[4 * w + 0] = dec8<0>(qw[w]) * INV_SCALE;
        qv[4 * w + 1] = dec8<1>(qw[w]) * INV_SCALE;
        qv[4 * w + 2] = dec8<2>(qw[w]) * INV_SCALE;
        qv[4 * w + 3] = dec8<3>(qw[w]) * INV_SCALE;
    }
    float* obase = outq + (size_t)b * (DC * HWs) + s0;
    float err = 0.f;
#pragma unroll
    for (int j = 0; j < 8; ++j) {
        size_t o = (size_t)(8 * g + j) * HWs;
        float d = qv[j] - zbase[o];
        obase[o] = qv[j];
        err = fmaf(d, d, err);
    }
#pragma unroll
    for (int j = 0; j < 8; ++j) {
        size_t o = (size_t)(32 + 8 * g + j) * HWs;
        float d = qv[8 + j] - zbase[o];
        obase[o] = qv[8 + j];
        err = fmaf(d, d, err);
    }

#pragma unroll
    for (int off = 32; off; off >>= 1) err += __shfl_down(err, off, 64);
    if (lane == 0) partial[wgid] = err;
}

// --- final loss reduction ---------------------------------------------------
__global__ __launch_bounds__(256) void vq_loss(const float* __restrict__ partial,
                                               float* __restrict__ loss_out) {
    float s = 0.f;
    for (int i = threadIdx.x; i < NWAVES; i += 256) s += partial[i];
#pragma unroll
    for (int off = 32; off; off >>= 1) s += __shfl_down(s, off, 64);
    __shared__ float red[4];
    if ((threadIdx.x & 63) == 0) red[threadIdx.x >> 6] = s;
    __syncthreads();
    if (threadIdx.x == 0)
        loss_out[0] = 1.25f * ((red[0] + red[1]) + (red[2] + red[3])) / 8388608.0f;
}

extern "C" void kernel_launch(void* const* d_in, const int* in_sizes, int n_in,
                              void* d_out, int out_size, void* d_ws, size_t ws_size,
                              hipStream_t stream) {
    const float* z   = (const float*)d_in[0];    // [32,64,64,64] f32
    const float* cbf = (const float*)d_in[1];    // [512,64] f32
    float* outq = (float*)d_out;                 // 8388608 + 1 (loss)
    float* loss = outq + 8388608;

    unsigned int* cb8 = (unsigned int*)d_ws;                   // 32 KB
    float* inib    = (float*)((char*)d_ws + 32768);            // 2 KB
    float* partial = (float*)((char*)d_ws + 32768 + 2048);     // 32 KB

    vq_prep<<<8, 256, 0, stream>>>(cbf, cb8, inib);
    vq_search<<<NWAVES / 8, 512, 0, stream>>>(z, cb8, inib, outq, partial);
    vq_loss<<<1, 256, 0, stream>>>(partial, loss);
}